// Round 9
// baseline (185.524 us; speedup 1.0000x reference)
//
#include <hip/hip_runtime.h>
#include <float.h>

// Grid dims from the reference
#define BDIM 4
#define ZDIM 6
#define YDIM 200
#define XDIM 176
#define CDIM 64
#define KSLOTS (BDIM * ZDIM * YDIM * XDIM)  // 844800
#define BINV 64                              // voxels per bin
#define NBIN (KSLOTS / BINV)                 // 13200
#define CAP1 64                              // fixed slots/bin, set1 (mean ~15)
#define CAP2 192                             // fixed slots/bin, set2 (mean ~61)
#define CAPT (CAP1 + CAP2)                   // 256 recs per bin
#define OVFCAP 16384

typedef float f32x4 __attribute__((ext_vector_type(4)));
typedef float f32x2 __attribute__((ext_vector_type(2)));

__device__ __forceinline__ int voxel_key4(const int4 c) {
    return ((c.x * ZDIM + c.y) * YDIM + c.z) * XDIM + c.w;
}
// monotonic float<->uint order encoding; 0u = "empty" sentinel (below all reals)
__device__ __forceinline__ unsigned ord_enc(float f) {
    unsigned u = __float_as_uint(f);
    return (u & 0x80000000u) ? ~u : (u | 0x80000000u);
}
__device__ __forceinline__ float ord_dec(unsigned u) {
    return (u & 0x80000000u) ? __uint_as_float(u & 0x7FFFFFFFu)
                             : __uint_as_float(~u);
}

// ---------------- single-pass fixed-capacity scatter ----------------
__global__ void scatter_fixed_kernel(const int* __restrict__ c1, int n1,
                                     const int* __restrict__ c2, int n2,
                                     int* __restrict__ cnt, int* __restrict__ dirty,
                                     int* __restrict__ ctr, int* __restrict__ dlist,
                                     int* __restrict__ ovf, int* __restrict__ recs) {
    int i = blockIdx.x * blockDim.x + threadIdx.x;
    int rec = 0, cslot = 0, bin = 0, capv = 0, rbase = 0;
    bool valid = false;
    if (i < n1) {
        int4 cc = *reinterpret_cast<const int4*>(c1 + (long long)i * 4);
        int key = voxel_key4(cc);
        bin = key >> 6;
        rec = (i << 6) | (key & 63);
        cslot = 2 * bin;     capv = CAP1; rbase = bin * CAPT;        valid = true;
    } else if (i < n1 + n2) {
        int j = i - n1;
        int4 cc = *reinterpret_cast<const int4*>(c2 + (long long)j * 4);
        int key = voxel_key4(cc);
        bin = key >> 6;
        rec = (j << 6) | (key & 63);
        cslot = 2 * bin + 1; capv = CAP2; rbase = bin * CAPT + CAP1; valid = true;
    }
    if (valid) {
        int c = atomicAdd(&cnt[cslot], 1);
        if (c < capv) {
            recs[rbase + c] = rec;
        } else {
            int o = atomicAdd(&ctr[1], 1);
            if (o < OVFCAP) { ovf[2 * o] = rec; ovf[2 * o + 1] = cslot; }
            if (atomicExch(&dirty[bin], 1) == 0) {
                int d = atomicAdd(&ctr[0], 1);
                dlist[d] = bin;
            }
        }
    }
}

// ---------------- fused bin-local accumulate ----------------
// One block per bin (64 voxels x 64 ch = 16KB LDS tile). float2 row reads:
// ONE vmem instruction per point (lane reads ch 2*lane, 2*lane+1) -> half
// the vmcnt/queue slots per byte vs dword loads. LDS atomics 2 lanes/bank.
__global__ __launch_bounds__(256) void fuse_kernel(
        const float* __restrict__ f1, const float* __restrict__ f2,
        const int* __restrict__ recs, const int* __restrict__ cnt,
        float* __restrict__ out) {
    __shared__ unsigned acc[BINV * CDIM];   // 16 KB (encoded uints, then floats)
    __shared__ int rl1[CAP1];
    __shared__ int rl2[CAP2];
    int b = blockIdx.x;
    int t = threadIdx.x;
    int c1 = cnt[2 * b], c2 = cnt[2 * b + 1];
    int ns1 = min(c1, CAP1), ns2 = min(c2, CAP2);
    const int rb = b * CAPT;

    #pragma unroll
    for (int k = 0; k < 16; ++k) acc[t + k * 256] = 0u;  // 0 = empty sentinel
    for (int i = t; i < ns2; i += 256) rl2[i] = recs[rb + CAP1 + i];
    for (int i = t; i < ns1; i += 256) rl1[i] = recs[rb + i];
    __syncthreads();

    int lane = t & 31;   // channel-pair lane (ch 2*lane, 2*lane+1)
    int grp  = t >> 5;   // 8 point-groups

    // ---- set2: scatter-max into LDS, 8 points/group/iter, float2 loads ----
    for (int base = 0; base < ns2; base += 64) {
        int i0 = base + grp * 8;
        int last = ns2 - 1;
        int rr[8]; f32x2 d[8];
        #pragma unroll
        for (int k = 0; k < 8; ++k) rr[k] = rl2[min(i0 + k, last)];
        #pragma unroll
        for (int k = 0; k < 8; ++k) {
            const f32x2* p = (const f32x2*)(f2 + (long long)(rr[k] >> 6) * CDIM);
            d[k] = p[lane];
        }
        #pragma unroll
        for (int k = 0; k < 8; ++k) {
            if (i0 + k < ns2) {
                int lv = (rr[k] & 63) * CDIM + 2 * lane;
                atomicMax(&acc[lv],     ord_enc(d[k].x));
                atomicMax(&acc[lv + 1], ord_enc(d[k].y));
            }
        }
    }
    __syncthreads();

    // in-place decode: encoded uint -> float bits (0u -> 0.0f)
    #pragma unroll
    for (int k = 0; k < 16; ++k) {
        int w = t + k * 256;
        unsigned u = acc[w];
        acc[w] = __float_as_uint((u == 0u) ? 0.f : ord_dec(u));
    }
    __syncthreads();

    float* facc = (float*)acc;

    // ---- set1: scatter-add onto decoded max, 4 points/group/iter ----
    for (int base = 0; base < ns1; base += 32) {
        int i0 = base + grp * 4;
        int last = ns1 - 1;
        int rr[4]; f32x2 d[4];
        #pragma unroll
        for (int k = 0; k < 4; ++k) rr[k] = rl1[min(i0 + k, last)];
        #pragma unroll
        for (int k = 0; k < 4; ++k) {
            const f32x2* p = (const f32x2*)(f1 + (long long)(rr[k] >> 6) * CDIM);
            d[k] = p[lane];
        }
        #pragma unroll
        for (int k = 0; k < 4; ++k) {
            if (i0 + k < ns1) {
                int lv = (rr[k] & 63) * CDIM + 2 * lane;
                atomicAdd(&facc[lv],     d[k].x);
                atomicAdd(&facc[lv + 1], d[k].y);
            }
        }
    }
    __syncthreads();

    // ---- writeout: contiguous 16KB, full-line nt stores ----
    float* ob = out + (long long)b * (BINV * CDIM);
    #pragma unroll
    for (int k = 0; k < 4; ++k) {
        int w = k * 1024 + t * 4;
        f32x4 val = *(f32x4*)&facc[w];
        __builtin_nontemporal_store(val, (f32x4*)(ob + w));
    }
}

// ---------------- dirty-bin exact recompute (statistically never runs) ----
__global__ __launch_bounds__(256) void fixup_kernel(
        const float* __restrict__ f1, const float* __restrict__ f2,
        const int* __restrict__ recs, const int* __restrict__ cnt,
        const int* __restrict__ ctr, const int* __restrict__ dlist,
        const int* __restrict__ ovf, float* __restrict__ out) {
    __shared__ unsigned acc[BINV * CDIM];
    int nd = ctr[0];
    int novf = min(ctr[1], OVFCAP);
    int t = threadIdx.x;
    int lane = t & 31, grp = t >> 5;
    for (int d = blockIdx.x; d < nd; d += gridDim.x) {
        int b = dlist[d];
        int c1 = cnt[2 * b], c2 = cnt[2 * b + 1];
        int ns1 = min(c1, CAP1), ns2 = min(c2, CAP2);
        #pragma unroll
        for (int k = 0; k < 16; ++k) acc[t + k * 256] = 0u;
        __syncthreads();
        for (int i = grp; i < ns2; i += 8) {
            int rec = recs[b * CAPT + CAP1 + i];
            const float* p = f2 + (long long)(rec >> 6) * CDIM;
            int lv = (rec & 63) * CDIM;
            atomicMax(&acc[lv + lane],      ord_enc(p[lane]));
            atomicMax(&acc[lv + lane + 32], ord_enc(p[lane + 32]));
        }
        for (int i = grp; i < novf; i += 8) {
            if (ovf[2 * i + 1] == 2 * b + 1) {
                int rec = ovf[2 * i];
                const float* p = f2 + (long long)(rec >> 6) * CDIM;
                int lv = (rec & 63) * CDIM;
                atomicMax(&acc[lv + lane],      ord_enc(p[lane]));
                atomicMax(&acc[lv + lane + 32], ord_enc(p[lane + 32]));
            }
        }
        __syncthreads();
        #pragma unroll
        for (int k = 0; k < 16; ++k) {
            int w = t + k * 256;
            unsigned u = acc[w];
            acc[w] = __float_as_uint((u == 0u) ? 0.f : ord_dec(u));
        }
        __syncthreads();
        float* facc = (float*)acc;
        for (int i = grp; i < ns1; i += 8) {
            int rec = recs[b * CAPT + i];
            const float* p = f1 + (long long)(rec >> 6) * CDIM;
            int lv = (rec & 63) * CDIM;
            atomicAdd(&facc[lv + lane],      p[lane]);
            atomicAdd(&facc[lv + lane + 32], p[lane + 32]);
        }
        for (int i = grp; i < novf; i += 8) {
            if (ovf[2 * i + 1] == 2 * b) {
                int rec = ovf[2 * i];
                const float* p = f1 + (long long)(rec >> 6) * CDIM;
                int lv = (rec & 63) * CDIM;
                atomicAdd(&facc[lv + lane],      p[lane]);
                atomicAdd(&facc[lv + lane + 32], p[lane + 32]);
            }
        }
        __syncthreads();
        float* ob = out + (long long)b * (BINV * CDIM);
        #pragma unroll
        for (int k = 0; k < 4; ++k) {
            int w = k * 1024 + t * 4;
            *(f32x4*)(ob + w) = *(f32x4*)&facc[w];
        }
        __syncthreads();
    }
}

// ---------------- fallback (atomic path, used only if ws too small) ----------

__global__ void fb_scatter_max(const float* __restrict__ feats, const int* __restrict__ coords,
                               unsigned* __restrict__ out, int npts) {
    long long i = (long long)blockIdx.x * blockDim.x + threadIdx.x;
    if (i >= (long long)npts * (CDIM / 4)) return;
    int pt = (int)(i >> 4), c4 = (int)(i & 15);
    int4 cc = *reinterpret_cast<const int4*>(coords + (long long)pt * 4);
    int key = voxel_key4(cc);
    float4 f = *reinterpret_cast<const float4*>(feats + (long long)pt * CDIM + c4 * 4);
    unsigned* dst = out + (long long)key * CDIM + c4 * 4;
    atomicMax(dst + 0, ord_enc(f.x));
    atomicMax(dst + 1, ord_enc(f.y));
    atomicMax(dst + 2, ord_enc(f.z));
    atomicMax(dst + 3, ord_enc(f.w));
}
__global__ void fb_decode(unsigned* __restrict__ buf, long long n4) {
    long long i = (long long)blockIdx.x * blockDim.x + threadIdx.x;
    if (i >= n4) return;
    uint4 u = reinterpret_cast<const uint4*>(buf)[i];
    float4 f;
    f.x = (u.x == 0u) ? 0.f : ord_dec(u.x);
    f.y = (u.y == 0u) ? 0.f : ord_dec(u.y);
    f.z = (u.z == 0u) ? 0.f : ord_dec(u.z);
    f.w = (u.w == 0u) ? 0.f : ord_dec(u.w);
    reinterpret_cast<float4*>(buf)[i] = f;
}
__global__ void fb_scatter_add(const float* __restrict__ feats, const int* __restrict__ coords,
                               float* __restrict__ out, int npts) {
    long long i = (long long)blockIdx.x * blockDim.x + threadIdx.x;
    if (i >= (long long)npts * (CDIM / 4)) return;
    int pt = (int)(i >> 4), c4 = (int)(i & 15);
    int4 cc = *reinterpret_cast<const int4*>(coords + (long long)pt * 4);
    int key = voxel_key4(cc);
    float4 f = *reinterpret_cast<const float4*>(feats + (long long)pt * CDIM + c4 * 4);
    float* dst = out + (long long)key * CDIM + c4 * 4;
    atomicAdd(dst + 0, f.x); atomicAdd(dst + 1, f.y);
    atomicAdd(dst + 2, f.z); atomicAdd(dst + 3, f.w);
}

extern "C" void kernel_launch(void* const* d_in, const int* in_sizes, int n_in,
                              void* d_out, int out_size, void* d_ws, size_t ws_size,
                              hipStream_t stream) {
    const float* feats1 = (const float*)d_in[0];
    const int*   coords1 = (const int*)d_in[1];
    const float* feats2 = (const float*)d_in[2];
    const int*   coords2 = (const int*)d_in[3];
    float* out = (float*)d_out;

    const int n1 = in_sizes[1] / 4;
    const int n2 = in_sizes[3] / 4;
    const int n12 = n1 + n2;
    const long long kc = (long long)KSLOTS * CDIM;

    // ws layout (ints): cnt[2*NBIN] | dirty[NBIN] | ctr[2] | dlist[NBIN] |
    //                   ovf[2*OVFCAP] | recs[NBIN*CAPT]
    const size_t needed = ((size_t)3 * NBIN + 2 + NBIN + 2 * OVFCAP
                           + (size_t)NBIN * CAPT) * sizeof(int);
    if (ws_size < needed) {
        hipMemsetAsync(d_out, 0, kc * sizeof(float), stream);
        long long t2 = (long long)n2 * (CDIM / 4);
        fb_scatter_max<<<(int)((t2 + 255) / 256), 256, 0, stream>>>(feats2, coords2,
                                                                    (unsigned*)out, n2);
        long long q = kc / 4;
        fb_decode<<<(int)((q + 255) / 256), 256, 0, stream>>>((unsigned*)out, q);
        long long t1 = (long long)n1 * (CDIM / 4);
        fb_scatter_add<<<(int)((t1 + 255) / 256), 256, 0, stream>>>(feats1, coords1, out, n1);
        return;
    }

    int* cnt   = (int*)d_ws;
    int* dirty = cnt + 2 * NBIN;
    int* ctr   = dirty + NBIN;
    int* dlist = ctr + 2;
    int* ovf   = dlist + NBIN;
    int* recs  = ovf + 2 * OVFCAP;

    // zero cnt + dirty + ctr (contiguous prefix, 158 KB)
    hipMemsetAsync(cnt, 0, ((size_t)3 * NBIN + 2) * sizeof(int), stream);

    int nb12 = (n12 + 255) / 256;
    scatter_fixed_kernel<<<nb12, 256, 0, stream>>>(coords1, n1, coords2, n2,
                                                   cnt, dirty, ctr, dlist, ovf, recs);
    fuse_kernel<<<NBIN, 256, 0, stream>>>(feats1, feats2, recs, cnt, out);
    fixup_kernel<<<64, 256, 0, stream>>>(feats1, feats2, recs, cnt, ctr, dlist, ovf, out);
}